// Round 3
// baseline (282.201 us; speedup 1.0000x reference)
//
#include <hip/hip_runtime.h>
#include <hip/hip_bf16.h>

#define NB 16
#define CDIM 256
#define NHEADS 8
#define DH 32
#define NSP 4096
#define O3 768

typedef __bf16 bf16;
typedef bf16 bf16x4 __attribute__((ext_vector_type(4)));
typedef bf16 bf16x8 __attribute__((ext_vector_type(8)));
typedef float f32x4 __attribute__((ext_vector_type(4)));
typedef float f32x16 __attribute__((ext_vector_type(16)));

static __device__ __forceinline__ float bf2f(bf16 x){ return (float)x; }
static __device__ __forceinline__ bf16 f2bf(float x){ return (bf16)x; }

// async global->LDS, 16B per lane; lds dst wave-uniform base + lane*16
static __device__ __forceinline__ void gld16(const bf16* g, bf16* l){
    __builtin_amdgcn_global_load_lds((const __attribute__((address_space(1))) void*)g,
                                     (__attribute__((address_space(3))) void*)l, 16, 0, 0);
}

// ---------------- K0: transpose+convert x[b][c][n] (fp32) -> xT[b][n][c] (bf16) ----------------
__global__ void k_transpose(const float* __restrict__ x, bf16* __restrict__ xT){
    __shared__ bf16 tile[64][72];
    int b = blockIdx.z;
    int c0 = blockIdx.y * 64;
    int n0 = blockIdx.x * 64;
    int t = threadIdx.x;
    const float* xb = x + (size_t)b * CDIM * NSP;
    #pragma unroll
    for (int i = 0; i < 4; ++i){
        int lin = i*256 + t;
        int c = lin >> 4;
        int n4 = (lin & 15) * 4;
        f32x4 f = *(const f32x4*)(xb + (size_t)(c0 + c)*NSP + n0 + n4);
        bf16x4 v4;
        #pragma unroll
        for (int j = 0; j < 4; ++j) v4[j] = f2bf(f[j]);
        *(bf16x4*)&tile[c][n4] = v4;
    }
    __syncthreads();
    bf16* xTb = xT + (size_t)b * NSP * CDIM;
    #pragma unroll
    for (int i = 0; i < 2; ++i){
        int lin = i*256 + t;
        int n = lin >> 3;
        int c8 = (lin & 7) * 8;
        bf16x8 v;
        #pragma unroll
        for (int j = 0; j < 8; ++j) v[j] = tile[c8+j][n];
        *(bf16x8*)(xTb + (size_t)(n0+n)*CDIM + c0 + c8) = v;
    }
}

// ---------------- K0b: convert w_qkv fp32 -> bf16 ----------------
__global__ void k_wcvt(const float* __restrict__ w, bf16* __restrict__ w2){
    int idx = (blockIdx.x*256 + threadIdx.x) * 4;
    f32x4 f = *(const f32x4*)(w + idx);
    bf16x4 v;
    #pragma unroll
    for (int j=0;j<4;j++) v[j] = f2bf(f[j]);
    *(bf16x4*)(w2 + idx) = v;
}

// ---------------- K1: qkv GEMM, 256 thr / 4 waves, 64-row n-panel (36KB LDS -> 4 blocks/CU) ----
// Block: one xT n-panel (64 rows x 256 cols, 32KB) x one mgrp (256 o-rows).
// Wave: 64 o x 64 n, acc[4][4]. B swizzle: slot(r,c) = r*32 + (c ^ (r&7)), 8 el/slot.
__global__ __launch_bounds__(256,4) void k_qkv(const bf16* __restrict__ w2,
                                               const bf16* __restrict__ xT,
                                               bf16* __restrict__ qT,
                                               bf16* __restrict__ kv){
    __shared__ union {
        bf16 Bs[16384];       // 64*32 slots * 8 el = 32 KB
        bf16 ep[256*72];      // k/v epilogue 256x72 el = 36KB; q path uses [64][264] = 33.8KB
    } sm;
    int bid = blockIdx.x;
    int xcd = bid & 7, slot = bid >> 3;      // 384 slots per XCD
    int mgrp = slot % 3;
    int nt = xcd*128 + slot/3;               // 0..1023
    int b  = nt >> 6;
    int n0 = (nt & 63) * 64;                 // one 64-wide y-line
    int og0 = mgrp * 256;
    int t = threadIdx.x;
    int wv = t >> 6, lane = t & 63;

    // ---- stage B panel: per wave 8 gld16 (rows wv*16 .. wv*16+15) ----
    #pragma unroll
    for (int j=0;j<8;j++){
        int base_r = wv*16 + j*2;
        int r = base_r + (lane>>5);
        int c = (lane & 31) ^ (r & 7);
        const bf16* g = xT + ((size_t)b*NSP + n0 + r)*CDIM + c*8;
        gld16(g, &sm.Bs[(size_t)base_r*256]);   // base + lane*16B covers slots base_r*32+lane
    }
    __syncthreads();

    // B-frag slot bases (k-invariant parts)
    int brow[4], brx[4];
    #pragma unroll
    for (int ni=0;ni<4;ni++){
        int r = ni*16 + (lane&15);
        brow[ni] = r*32; brx[ni] = r & 7;
    }
    int arow = og0 + wv*64 + (lane&15);      // + mi*16
    int acol = (lane>>4)*8;                  // + k0*32

    f32x4 acc[4][4];
    #pragma unroll
    for (int i=0;i<16;i++) ((f32x4*)acc)[i] = (f32x4){0.f,0.f,0.f,0.f};

    bf16x8 af[4], an[4];
    #pragma unroll
    for (int mi=0;mi<4;mi++)
        af[mi] = *(const bf16x8*)(w2 + (size_t)(arow + mi*16)*CDIM + acol);
    #pragma unroll
    for (int k0=0;k0<8;k0++){
        if (k0 < 7){
            #pragma unroll
            for (int mi=0;mi<4;mi++)
                an[mi] = *(const bf16x8*)(w2 + (size_t)(arow + mi*16)*CDIM + (k0+1)*32 + acol);
        }
        int cbase = (lane>>4) + k0*4;
        bf16x8 bfr[4];
        #pragma unroll
        for (int ni=0;ni<4;ni++)
            bfr[ni] = *(const bf16x8*)&sm.Bs[(size_t)(brow[ni] + (cbase ^ brx[ni]))*8];
        #pragma unroll
        for (int mi=0;mi<4;mi++)
            #pragma unroll
            for (int ni=0;ni<4;ni++)
                acc[mi][ni] = __builtin_amdgcn_mfma_f32_16x16x32_bf16(af[mi], bfr[ni], acc[mi][ni], 0, 0, 0);
        #pragma unroll
        for (int mi=0;mi<4;mi++) af[mi] = an[mi];
    }
    __syncthreads();   // all waves done with Bs; safe to overlay ep

    if (mgrp == 0){
        // ---- fused q softmax over d; wave covers heads 2wv, 2wv+1 (mi pairs) ----
        #pragma unroll
        for (int ni=0;ni<4;ni++)
            #pragma unroll
            for (int hp=0;hp<2;hp++){
                float mx = -1e30f;
                #pragma unroll
                for (int mi=2*hp; mi<2*hp+2; mi++)
                    #pragma unroll
                    for (int r=0;r<4;r++) mx = fmaxf(mx, acc[mi][ni][r]);
                mx = fmaxf(mx, __shfl_xor(mx, 16, 64));
                mx = fmaxf(mx, __shfl_xor(mx, 32, 64));
                float s = 0.f;
                #pragma unroll
                for (int mi=2*hp; mi<2*hp+2; mi++)
                    #pragma unroll
                    for (int r=0;r<4;r++){
                        float e = __expf(acc[mi][ni][r] - mx);
                        acc[mi][ni][r] = e; s += e;
                    }
                s += __shfl_xor(s, 16, 64);
                s += __shfl_xor(s, 32, 64);
                float inv = 1.f/s;
                #pragma unroll
                for (int mi=2*hp; mi<2*hp+2; mi++)
                    #pragma unroll
                    for (int r=0;r<4;r++) acc[mi][ni][r] *= inv;
            }
        // dump transposed: ep[n_loc 0..63][o_loc 0..255], row stride 264 el
        #pragma unroll
        for (int mi=0;mi<4;mi++)
            #pragma unroll
            for (int ni=0;ni<4;ni++){
                int n_loc = ni*16 + (lane&15);
                int o_loc = wv*64 + mi*16 + (lane>>4)*4;
                bf16x4 v4;
                #pragma unroll
                for (int r=0;r<4;r++) v4[r] = f2bf(acc[mi][ni][r]);
                *(bf16x4*)&sm.ep[n_loc*264 + o_loc] = v4;
            }
        __syncthreads();
        bf16* qTb = qT + (size_t)b * NSP * CDIM;
        // 64 rows x 32 segs = 2048 tasks, 8 per thread; full 256-wide qT rows
        #pragma unroll
        for (int p=0;p<8;p++){
            int task = p*256 + t;
            int n_loc = task >> 5, seg = task & 31;
            bf16x8 v = *(const bf16x8*)&sm.ep[n_loc*264 + seg*8];
            *(bf16x8*)(qTb + (size_t)(n0+n_loc)*CDIM + seg*8) = v;
        }
    } else {
        if (mgrp == 1){
            // ---- fused k softmax over y: full 64-wide line = 4 ni x 16 lanes ----
            #pragma unroll
            for (int mi=0;mi<4;mi++)
                #pragma unroll
                for (int r=0;r<4;r++){
                    float mx = -1e30f;
                    #pragma unroll
                    for (int ni=0;ni<4;ni++) mx = fmaxf(mx, acc[mi][ni][r]);
                    #pragma unroll
                    for (int msk=1; msk<16; msk<<=1) mx = fmaxf(mx, __shfl_xor(mx, msk, 64));
                    float s = 0.f;
                    #pragma unroll
                    for (int ni=0;ni<4;ni++){
                        float e = __expf(acc[mi][ni][r] - mx);
                        acc[mi][ni][r] = e; s += e;
                    }
                    #pragma unroll
                    for (int msk=1; msk<16; msk<<=1) s += __shfl_xor(s, msk, 64);
                    float inv = 1.f/s;
                    #pragma unroll
                    for (int ni=0;ni<4;ni++) acc[mi][ni][r] *= inv;
                }
        }
        // dump: ep[c_loc 0..255][n_loc 0..63], row stride 72 el (144B, 16B-mult)
        #pragma unroll
        for (int mi=0;mi<4;mi++)
            #pragma unroll
            for (int ni=0;ni<4;ni++){
                int n_loc = ni*16 + (lane&15);
                int c_loc = wv*64 + mi*16 + (lane>>4)*4;
                #pragma unroll
                for (int r=0;r<4;r++) sm.ep[(c_loc+r)*72 + n_loc] = f2bf(acc[mi][ni][r]);
            }
        __syncthreads();
        bf16* kvb = kv + (size_t)b * 512 * NSP;
        int c0t = (mgrp == 1) ? 0 : 256;
        // 256 rows x 8 segs = 2048 tasks, 8 per thread
        #pragma unroll
        for (int p=0;p<8;p++){
            int task = p*256 + t;
            int c_loc = task >> 3, seg = task & 7;
            bf16x8 v = *(const bf16x8*)&sm.ep[c_loc*72 + seg*8];
            *(bf16x8*)(kvb + (size_t)(c0t+c_loc)*NSP + n0 + seg*8) = v;
        }
    }
}

// ---------------- K4: ctx partials via MFMA 32x32x16, split-K 32-way ----------------
__global__ __launch_bounds__(256) void k_context(const bf16* __restrict__ kv,
                                                 float* __restrict__ ctx_p){
    int blk = blockIdx.x;          // 1024 blocks
    int bh = blk >> 3;
    int chunk = blk & 7;
    int b = bh >> 3, h = bh & 7;
    int wave = threadIdx.x >> 6, lane = threadIdx.x & 63;
    int nbase = chunk*512 + wave*128;
    int row = lane & 31;
    int koff = (lane >> 5) * 8;
    const bf16* kp = kv + ((size_t)b*512 +       h*DH + row)*NSP + nbase + koff;
    const bf16* vp = kv + ((size_t)b*512 + 256 + h*DH + row)*NSP + nbase + koff;
    f32x16 acc;
    #pragma unroll
    for (int i=0;i<16;i++) acc[i] = 0.f;
    #pragma unroll
    for (int s=0; s<8; s++){
        bf16x8 a  = *(const bf16x8*)(kp + s*16);
        bf16x8 bb = *(const bf16x8*)(vp + s*16);
        acc = __builtin_amdgcn_mfma_f32_32x32x16_bf16(a, bb, acc, 0, 0, 0);
    }
    float* dst = ctx_p + ((size_t)bh*32 + chunk*4 + wave)*1024;
    #pragma unroll
    for (int r=0;r<16;r++){
        int d = (r&3) + 8*(r>>2) + 4*(lane>>5);
        dst[d*32 + (lane&31)] = acc[r];
    }
}

// ---------------- K5: reduce partials + W2 = w_out x ctx (per b,h) ----------------
__global__ void k_merge(const float* __restrict__ w_out, const float* __restrict__ ctx_p,
                        bf16* __restrict__ W2){
    __shared__ float ctxs[32][32];
    int bh = blockIdx.x;
    int b = bh >> 3, h = bh & 7;
    int t = threadIdx.x;
    const float* base = ctx_p + (size_t)bh*32*1024;
    #pragma unroll
    for (int i=0;i<4;i++){
        int idx = i*256 + t;
        float s = 0.f;
        #pragma unroll
        for (int p=0;p<32;p++) s += base[p*1024 + idx];
        ((float*)ctxs)[idx] = s;
    }
    __syncthreads();
    int o = t;
    const float* wrow = w_out + (size_t)o*CDIM + h*DH;
    float wv[32];
    #pragma unroll
    for (int d=0;d<32;d++) wv[d] = wrow[d];
    bf16* dst = W2 + ((size_t)b*CDIM + o)*CDIM + h*DH;
    #pragma unroll
    for (int g=0;g<4;g++){
        bf16x8 o8;
        #pragma unroll
        for (int jj=0;jj<8;jj++){
            int e = g*8 + jj;
            float s = 0.f;
            #pragma unroll
            for (int d=0;d<32;d++) s += wv[d]*ctxs[d][e];
            o8[jj] = f2bf(s);
        }
        *(bf16x8*)(dst + g*8) = o8;
    }
}

// ---------------- K6: y = W2[b] @ q~T + b_out + LayerNorm; 32-n panel (36KB LDS) ----------------
__global__ __launch_bounds__(256,4) void k_out_ln(const bf16* __restrict__ W2,
                                                  const bf16* __restrict__ qT,
                                                  const float* __restrict__ bout,
                                                  const float* __restrict__ gamma,
                                                  const float* __restrict__ beta,
                                                  float* __restrict__ out){
    __shared__ union {
        bf16 Bs[8192];       // 32 rows * 32 slots * 8 el = 16 KB
        float Y[256*33];     // 33.8 KB
    } sm;
    __shared__ float red[2][8][32];
    __shared__ float mu_s[32], rstd_s[32];
    int bid = blockIdx.x;
    int xcd = bid & 7, slot = bid >> 3;      // 256 slots per XCD
    int b  = slot >> 4;
    int n0 = (xcd*16 + (slot & 15)) * 32;
    int t = threadIdx.x, wv = t>>6, lane = t&63;

    // ---- stage qT panel [n0..n0+32][0..256]: per wave 4 gld16 (rows wv*8..wv*8+7) ----
    const bf16* qTb = qT + (size_t)b * NSP * CDIM;
    #pragma unroll
    for (int j=0;j<4;j++){
        int base_r = wv*8 + j*2;
        int r = base_r + (lane>>5);
        int c = (lane & 31) ^ (r & 7);
        gld16(qTb + (size_t)(n0 + r)*CDIM + c*8, &sm.Bs[(size_t)base_r*256]);
    }
    __syncthreads();

    int brow[2], brx[2];
    #pragma unroll
    for (int ni=0;ni<2;ni++){
        int r = ni*16 + (lane&15);
        brow[ni] = r*32; brx[ni] = r & 7;
    }
    const bf16* Ab = W2 + (size_t)b*CDIM*CDIM;
    int arow = wv*64 + (lane&15);
    int acol = (lane>>4)*8;

    f32x4 acc[4][2];
    #pragma unroll
    for (int i=0;i<8;i++) ((f32x4*)acc)[i] = (f32x4){0.f,0.f,0.f,0.f};

    bf16x8 af[4], an[4];
    #pragma unroll
    for (int mi=0;mi<4;mi++)
        af[mi] = *(const bf16x8*)(Ab + (size_t)(arow + mi*16)*CDIM + acol);
    #pragma unroll
    for (int k0=0;k0<8;k0++){
        if (k0 < 7){
            #pragma unroll
            for (int mi=0;mi<4;mi++)
                an[mi] = *(const bf16x8*)(Ab + (size_t)(arow + mi*16)*CDIM + (k0+1)*32 + acol);
        }
        int cbase = (lane>>4) + k0*4;
        bf16x8 bfr[2];
        #pragma unroll
        for (int ni=0;ni<2;ni++)
            bfr[ni] = *(const bf16x8*)&sm.Bs[(size_t)(brow[ni] + (cbase ^ brx[ni]))*8];
        #pragma unroll
        for (int mi=0;mi<4;mi++)
            #pragma unroll
            for (int ni=0;ni<2;ni++)
                acc[mi][ni] = __builtin_amdgcn_mfma_f32_16x16x32_bf16(af[mi], bfr[ni], acc[mi][ni], 0, 0, 0);
        #pragma unroll
        for (int mi=0;mi<4;mi++) af[mi] = an[mi];
    }
    __syncthreads();   // done with Bs; overlay Y
    #pragma unroll
    for (int mi=0;mi<4;mi++)
        #pragma unroll
        for (int ni=0;ni<2;ni++)
            #pragma unroll
            for (int r=0;r<4;r++){
                int o = wv*64 + mi*16 + (lane>>4)*4 + r;
                int n = ni*16 + (lane&15);
                sm.Y[o*33 + n] = acc[mi][ni][r];
            }
    __syncthreads();
    int n = t & 31, q = t >> 5;              // 8 o-groups of 32
    float s = 0.f, s2 = 0.f;
    for (int o=32*q; o<32*q+32; o++){
        float y = sm.Y[o*33+n] + bout[o];
        s += y; s2 += y*y;
    }
    red[0][q][n] = s; red[1][q][n] = s2;
    __syncthreads();
    if (t < 32){
        float S = 0.f, S2 = 0.f;
        #pragma unroll
        for (int p=0;p<8;p++){ S += red[0][p][t]; S2 += red[1][p][t]; }
        float mu = S * (1.f/256.f);
        float var = S2*(1.f/256.f) - mu*mu;
        mu_s[t] = mu; rstd_s[t] = rsqrtf(var + 1e-5f);
    }
    __syncthreads();
    float mu = mu_s[n], rstd = rstd_s[n];
    size_t ob = (size_t)b*CDIM*NSP + n0 + n;
    for (int o=32*q; o<32*q+32; o++){
        float y = sm.Y[o*33+n] + bout[o];
        out[ob + (size_t)o*NSP] = (y - mu)*rstd*gamma[o] + beta[o];
    }
}

extern "C" void kernel_launch(void* const* d_in, const int* in_sizes, int n_in,
                              void* d_out, int out_size, void* d_ws, size_t ws_size,
                              hipStream_t stream){
    const float* x     = (const float*)d_in[0];
    const float* w_qkv = (const float*)d_in[1];
    const float* w_out = (const float*)d_in[2];
    const float* b_out = (const float*)d_in[3];
    const float* gamma = (const float*)d_in[4];
    const float* beta  = (const float*)d_in[5];
    float* out = (float*)d_out;
    char* ws = (char*)d_ws;
    // ws layout (bytes):
    //   xT    bf16 [16][4096][256] : 0          .. 33,554,432   (dead after k_qkv)
    //   ctx_p f32  [128][32][1024] : 0          .. 16,777,216   (overlaps dead xT)
    //   qT    bf16 [16][4096][256] : 33,554,432 .. 67,108,864
    //   kv    bf16 [16][512][4096] : 67,108,864 .. 134,217,728
    //   W2    bf16 [16][256][256]  : 134,742,016 .. 136,839,168
    //   w2    bf16 [768][256]      : 136,839,168 .. 137,232,384
    bf16*  xT    = (bf16*) ws;
    float* ctx_p = (float*)ws;
    bf16*  qT    = (bf16*)(ws + 33554432ull);
    bf16*  kv    = (bf16*)(ws + 67108864ull);
    bf16*  W2    = (bf16*)(ws + 134742016ull);
    bf16*  w2    = (bf16*)(ws + 136839168ull);

    k_wcvt     <<<dim3(192),       256, 0, stream>>>(w_qkv, w2);
    k_transpose<<<dim3(64, 4, NB), 256, 0, stream>>>(x, xT);
    k_qkv      <<<dim3(3072),      256, 0, stream>>>(w2, xT, qT, kv);
    k_context  <<<dim3(1024),      256, 0, stream>>>(kv, ctx_p);
    k_merge    <<<dim3(128),       256, 0, stream>>>(w_out, ctx_p, W2);
    k_out_ln   <<<dim3(2048),      256, 0, stream>>>(W2, qT, b_out, gamma, beta, out);
}

// Round 5
// 267.155 us; speedup vs baseline: 1.0563x; 1.0563x over previous
//
#include <hip/hip_runtime.h>
#include <hip/hip_bf16.h>

#define NB 16
#define CDIM 256
#define NHEADS 8
#define DH 32
#define NSP 4096
#define O3 768

typedef __bf16 bf16;
typedef bf16 bf16x4 __attribute__((ext_vector_type(4)));
typedef bf16 bf16x8 __attribute__((ext_vector_type(8)));
typedef float f32x4 __attribute__((ext_vector_type(4)));
typedef float f32x16 __attribute__((ext_vector_type(16)));

static __device__ __forceinline__ float bf2f(bf16 x){ return (float)x; }
static __device__ __forceinline__ bf16 f2bf(float x){ return (bf16)x; }

// async global->LDS, 16B per lane; lds dst wave-uniform base + lane*16
static __device__ __forceinline__ void gld16(const bf16* g, bf16* l){
    __builtin_amdgcn_global_load_lds((const __attribute__((address_space(1))) void*)g,
                                     (__attribute__((address_space(3))) void*)l, 16, 0, 0);
}

// ---------------- K0: transpose+convert x[b][c][n] (fp32) -> xT[b][n][c] (bf16) ----------------
__global__ void k_transpose(const float* __restrict__ x, bf16* __restrict__ xT){
    __shared__ bf16 tile[64][72];
    int b = blockIdx.z;
    int c0 = blockIdx.y * 64;
    int n0 = blockIdx.x * 64;
    int t = threadIdx.x;
    const float* xb = x + (size_t)b * CDIM * NSP;
    #pragma unroll
    for (int i = 0; i < 4; ++i){
        int lin = i*256 + t;
        int c = lin >> 4;
        int n4 = (lin & 15) * 4;
        f32x4 f = *(const f32x4*)(xb + (size_t)(c0 + c)*NSP + n0 + n4);
        bf16x4 v4;
        #pragma unroll
        for (int j = 0; j < 4; ++j) v4[j] = f2bf(f[j]);
        *(bf16x4*)&tile[c][n4] = v4;
    }
    __syncthreads();
    bf16* xTb = xT + (size_t)b * NSP * CDIM;
    #pragma unroll
    for (int i = 0; i < 2; ++i){
        int lin = i*256 + t;
        int n = lin >> 3;
        int c8 = (lin & 7) * 8;
        bf16x8 v;
        #pragma unroll
        for (int j = 0; j < 8; ++j) v[j] = tile[c8+j][n];
        *(bf16x8*)(xTb + (size_t)(n0+n)*CDIM + c0 + c8) = v;
    }
}

// ---------------- K0b: convert w_qkv fp32 -> bf16 ----------------
__global__ void k_wcvt(const float* __restrict__ w, bf16* __restrict__ w2){
    int idx = (blockIdx.x*256 + threadIdx.x) * 4;
    f32x4 f = *(const f32x4*)(w + idx);
    bf16x4 v;
    #pragma unroll
    for (int j=0;j<4;j++) v[j] = f2bf(f[j]);
    *(bf16x4*)(w2 + idx) = v;
}

// ---------------- K1: qkv GEMM. Block = one 128-n panel (64KB, staged once) x one mgrp
// (256 o-rows). 4 waves; wave = 64 o x 128 n, acc[4][8], 256 MFMA/wave.
// B swizzle: slot(r,c) = r*32 + (c ^ (r&7)), 8 el/slot. Epilogue via 34.8KB ep overlay,
// two phases (mi-pairs 0,1 then 2,3) with packed row index.
__global__ __launch_bounds__(256,2) void k_qkv(const bf16* __restrict__ w2,
                                               const bf16* __restrict__ xT,
                                               bf16* __restrict__ qT,
                                               bf16* __restrict__ kv){
    __shared__ union {
        bf16 Bs[32768];       // 128*32 slots * 8 el = 64 KB
        bf16 ep[128*136];     // 34.8 KB epilogue buffer (row stride 136 el = 272B)
    } sm;
    int bid = blockIdx.x;
    int xcd = bid & 7, slot = bid >> 3;      // 192 slots per XCD
    int mgrp = slot % 3;
    int nt = xcd*64 + slot/3;                // 0..511
    int b  = nt >> 5;
    int n0 = (nt & 31) * 128;
    int og0 = mgrp * 256;
    int t = threadIdx.x;
    int wv = t >> 6, lane = t & 63;

    // ---- stage whole B panel: per wave 16 gld16 (rows wv*32 .. wv*32+31) ----
    #pragma unroll
    for (int j=0;j<16;j++){
        int base_r = wv*32 + j*2;
        int r = base_r + (lane>>5);
        int c = (lane & 31) ^ (r & 7);
        const bf16* g = xT + ((size_t)b*NSP + n0 + r)*CDIM + c*8;
        gld16(g, &sm.Bs[(size_t)base_r*256]);   // base + lane*16B covers slots base_r*32+lane
    }
    __syncthreads();

    // B-frag slot bases (k-invariant parts)
    int brow[8], brx[8];
    #pragma unroll
    for (int ni=0;ni<8;ni++){
        int r = ni*16 + (lane&15);
        brow[ni] = r*32; brx[ni] = r & 7;
    }
    int arow = og0 + wv*64 + (lane&15);      // + mi*16
    int acol = (lane>>4)*8;                  // + k0*32

    f32x4 acc[4][8];
    #pragma unroll
    for (int i=0;i<32;i++) ((f32x4*)acc)[i] = (f32x4){0.f,0.f,0.f,0.f};

    bf16x8 af[4], an[4];
    #pragma unroll
    for (int mi=0;mi<4;mi++)
        af[mi] = *(const bf16x8*)(w2 + (size_t)(arow + mi*16)*CDIM + acol);
    #pragma unroll
    for (int k0=0;k0<8;k0++){
        if (k0 < 7){
            #pragma unroll
            for (int mi=0;mi<4;mi++)
                an[mi] = *(const bf16x8*)(w2 + (size_t)(arow + mi*16)*CDIM + (k0+1)*32 + acol);
        }
        int cbase = (lane>>4) + k0*4;
        bf16x8 bfr[8];
        #pragma unroll
        for (int ni=0;ni<8;ni++)
            bfr[ni] = *(const bf16x8*)&sm.Bs[(size_t)(brow[ni] + (cbase ^ brx[ni]))*8];
        #pragma unroll
        for (int mi=0;mi<4;mi++)
            #pragma unroll
            for (int ni=0;ni<8;ni++)
                acc[mi][ni] = __builtin_amdgcn_mfma_f32_16x16x32_bf16(af[mi], bfr[ni], acc[mi][ni], 0, 0, 0);
        #pragma unroll
        for (int mi=0;mi<4;mi++) af[mi] = an[mi];
    }
    __syncthreads();   // all waves done with Bs; safe to overlay ep

    if (mgrp == 0){
        // ---- fused q softmax over d; wave's 64 o-rows = heads 2wv (mi 0,1), 2wv+1 (mi 2,3) ----
        #pragma unroll
        for (int ni=0;ni<8;ni++)
            #pragma unroll
            for (int hp=0;hp<2;hp++){
                float mx = -1e30f;
                #pragma unroll
                for (int mi=2*hp; mi<2*hp+2; mi++)
                    #pragma unroll
                    for (int r=0;r<4;r++) mx = fmaxf(mx, acc[mi][ni][r]);
                mx = fmaxf(mx, __shfl_xor(mx, 16, 64));
                mx = fmaxf(mx, __shfl_xor(mx, 32, 64));
                float s = 0.f;
                #pragma unroll
                for (int mi=2*hp; mi<2*hp+2; mi++)
                    #pragma unroll
                    for (int r=0;r<4;r++){
                        float e = __expf(acc[mi][ni][r] - mx);
                        acc[mi][ni][r] = e; s += e;
                    }
                s += __shfl_xor(s, 16, 64);
                s += __shfl_xor(s, 32, 64);
                float inv = 1.f/s;
                #pragma unroll
                for (int mi=2*hp; mi<2*hp+2; mi++)
                    #pragma unroll
                    for (int r=0;r<4;r++) acc[mi][ni][r] *= inv;
            }
        bf16* qTb = qT + (size_t)b * NSP * CDIM;
        // two phases: p=0 dumps mi 0,1 (packed o = wv*32 + (mi&1)*16 + ...), p=1 dumps mi 2,3.
        // actual o = (packed>>5)*64 + p*32 + (packed&31)
        #pragma unroll
        for (int p=0;p<2;p++){
            if (p) __syncthreads();
            #pragma unroll
            for (int mi=2*p; mi<2*p+2; mi++)
                #pragma unroll
                for (int ni=0;ni<8;ni++){
                    int n_loc = ni*16 + (lane&15);
                    int o_p = wv*32 + (mi&1)*16 + (lane>>4)*4;
                    bf16x4 v4;
                    #pragma unroll
                    for (int r=0;r<4;r++) v4[r] = f2bf(acc[mi][ni][r]);
                    *(bf16x4*)&sm.ep[n_loc*136 + o_p] = v4;
                }
            __syncthreads();
            #pragma unroll
            for (int i=0;i<8;i++){
                int task = i*256 + t;
                int n_loc = task >> 4, seg = task & 15;
                bf16x8 v = *(const bf16x8*)&sm.ep[n_loc*136 + seg*8];
                *(bf16x8*)(qTb + (size_t)(n0+n_loc)*CDIM + (seg>>2)*64 + p*32 + (seg&3)*8) = v;
            }
        }
    } else {
        if (mgrp == 1){
            // ---- fused k softmax over y: 64-col groups (ni 0..3 / 4..7) x 16 lanes ----
            #pragma unroll
            for (int mi=0;mi<4;mi++)
                #pragma unroll
                for (int r=0;r<4;r++)
                    #pragma unroll
                    for (int grp=0;grp<2;grp++){
                        float mx = -1e30f;
                        #pragma unroll
                        for (int q=0;q<4;q++) mx = fmaxf(mx, acc[mi][grp*4+q][r]);
                        #pragma unroll
                        for (int msk=1; msk<16; msk<<=1) mx = fmaxf(mx, __shfl_xor(mx, msk, 64));
                        float s = 0.f;
                        #pragma unroll
                        for (int q=0;q<4;q++){
                            float e = __expf(acc[mi][grp*4+q][r] - mx);
                            acc[mi][grp*4+q][r] = e; s += e;
                        }
                        #pragma unroll
                        for (int msk=1; msk<16; msk<<=1) s += __shfl_xor(s, msk, 64);
                        float inv = 1.f/s;
                        #pragma unroll
                        for (int q=0;q<4;q++) acc[mi][grp*4+q][r] *= inv;
                    }
        }
        bf16* kvb = kv + (size_t)b * 512 * NSP;
        int c0t = (mgrp == 1) ? 0 : 256;
        // two phases: p=0 dumps mi 0,1 (packed c = wv*32 + (mi&1)*16 + ...), p=1 dumps mi 2,3.
        // actual c = (packed>>5)*64 + p*32 + (packed&31); full 256B row written per task.
        #pragma unroll
        for (int p=0;p<2;p++){
            if (p) __syncthreads();
            #pragma unroll
            for (int mi=2*p; mi<2*p+2; mi++)
                #pragma unroll
                for (int ni=0;ni<8;ni++){
                    int n_loc = ni*16 + (lane&15);
                    int c_p = wv*32 + (mi&1)*16 + (lane>>4)*4;
                    #pragma unroll
                    for (int r=0;r<4;r++) sm.ep[(c_p+r)*136 + n_loc] = f2bf(acc[mi][ni][r]);
                }
            __syncthreads();
            #pragma unroll
            for (int i=0;i<8;i++){
                int task = i*256 + t;
                int c_p = task >> 4, seg = task & 15;
                bf16x8 v = *(const bf16x8*)&sm.ep[c_p*136 + seg*8];
                int c_act = (c_p>>5)*64 + p*32 + (c_p&31);
                *(bf16x8*)(kvb + (size_t)(c0t+c_act)*NSP + n0 + seg*8) = v;
            }
        }
    }
}

// ---------------- K4: ctx partials via MFMA 32x32x16, split-K 32-way ----------------
__global__ __launch_bounds__(256) void k_context(const bf16* __restrict__ kv,
                                                 float* __restrict__ ctx_p){
    int blk = blockIdx.x;          // 1024 blocks
    int bh = blk >> 3;
    int chunk = blk & 7;
    int b = bh >> 3, h = bh & 7;
    int wave = threadIdx.x >> 6, lane = threadIdx.x & 63;
    int nbase = chunk*512 + wave*128;
    int row = lane & 31;
    int koff = (lane >> 5) * 8;
    const bf16* kp = kv + ((size_t)b*512 +       h*DH + row)*NSP + nbase + koff;
    const bf16* vp = kv + ((size_t)b*512 + 256 + h*DH + row)*NSP + nbase + koff;
    f32x16 acc;
    #pragma unroll
    for (int i=0;i<16;i++) acc[i] = 0.f;
    #pragma unroll
    for (int s=0; s<8; s++){
        bf16x8 a  = *(const bf16x8*)(kp + s*16);
        bf16x8 bb = *(const bf16x8*)(vp + s*16);
        acc = __builtin_amdgcn_mfma_f32_32x32x16_bf16(a, bb, acc, 0, 0, 0);
    }
    float* dst = ctx_p + ((size_t)bh*32 + chunk*4 + wave)*1024;
    #pragma unroll
    for (int r=0;r<16;r++){
        int d = (r&3) + 8*(r>>2) + 4*(lane>>5);
        dst[d*32 + (lane&31)] = acc[r];
    }
}

// ---------------- K5: reduce partials + W2 = w_out x ctx (per b,h) ----------------
__global__ void k_merge(const float* __restrict__ w_out, const float* __restrict__ ctx_p,
                        bf16* __restrict__ W2){
    __shared__ float ctxs[32][32];
    int bh = blockIdx.x;
    int b = bh >> 3, h = bh & 7;
    int t = threadIdx.x;
    const float* base = ctx_p + (size_t)bh*32*1024;
    #pragma unroll
    for (int i=0;i<4;i++){
        int idx = i*256 + t;
        float s = 0.f;
        #pragma unroll
        for (int p=0;p<32;p++) s += base[p*1024 + idx];
        ((float*)ctxs)[idx] = s;
    }
    __syncthreads();
    int o = t;
    const float* wrow = w_out + (size_t)o*CDIM + h*DH;
    float wv[32];
    #pragma unroll
    for (int d=0;d<32;d++) wv[d] = wrow[d];
    bf16* dst = W2 + ((size_t)b*CDIM + o)*CDIM + h*DH;
    #pragma unroll
    for (int g=0;g<4;g++){
        bf16x8 o8;
        #pragma unroll
        for (int jj=0;jj<8;jj++){
            int e = g*8 + jj;
            float s = 0.f;
            #pragma unroll
            for (int d=0;d<32;d++) s += wv[d]*ctxs[d][e];
            o8[jj] = f2bf(s);
        }
        *(bf16x8*)(dst + g*8) = o8;
    }
}

// ---------------- K6: y = W2[b] @ q~T + b_out + LayerNorm; 32-n panel (36KB LDS) ----------------
__global__ __launch_bounds__(256,4) void k_out_ln(const bf16* __restrict__ W2,
                                                  const bf16* __restrict__ qT,
                                                  const float* __restrict__ bout,
                                                  const float* __restrict__ gamma,
                                                  const float* __restrict__ beta,
                                                  float* __restrict__ out){
    __shared__ union {
        bf16 Bs[8192];       // 32 rows * 32 slots * 8 el = 16 KB
        float Y[256*33];     // 33.8 KB
    } sm;
    __shared__ float red[2][8][32];
    __shared__ float mu_s[32], rstd_s[32];
    int bid = blockIdx.x;
    int xcd = bid & 7, slot = bid >> 3;      // 256 slots per XCD
    int b  = slot >> 4;
    int n0 = (xcd*16 + (slot & 15)) * 32;
    int t = threadIdx.x, wv = t>>6, lane = t&63;

    // ---- stage qT panel [n0..n0+32][0..256]: per wave 4 gld16 (rows wv*8..wv*8+7) ----
    const bf16* qTb = qT + (size_t)b * NSP * CDIM;
    #pragma unroll
    for (int j=0;j<4;j++){
        int base_r = wv*8 + j*2;
        int r = base_r + (lane>>5);
        int c = (lane & 31) ^ (r & 7);
        gld16(qTb + (size_t)(n0 + r)*CDIM + c*8, &sm.Bs[(size_t)base_r*256]);
    }
    __syncthreads();

    int brow[2], brx[2];
    #pragma unroll
    for (int ni=0;ni<2;ni++){
        int r = ni*16 + (lane&15);
        brow[ni] = r*32; brx[ni] = r & 7;
    }
    const bf16* Ab = W2 + (size_t)b*CDIM*CDIM;
    int arow = wv*64 + (lane&15);
    int acol = (lane>>4)*8;

    f32x4 acc[4][2];
    #pragma unroll
    for (int i=0;i<8;i++) ((f32x4*)acc)[i] = (f32x4){0.f,0.f,0.f,0.f};

    bf16x8 af[4], an[4];
    #pragma unroll
    for (int mi=0;mi<4;mi++)
        af[mi] = *(const bf16x8*)(Ab + (size_t)(arow + mi*16)*CDIM + acol);
    #pragma unroll
    for (int k0=0;k0<8;k0++){
        if (k0 < 7){
            #pragma unroll
            for (int mi=0;mi<4;mi++)
                an[mi] = *(const bf16x8*)(Ab + (size_t)(arow + mi*16)*CDIM + (k0+1)*32 + acol);
        }
        int cbase = (lane>>4) + k0*4;
        bf16x8 bfr[2];
        #pragma unroll
        for (int ni=0;ni<2;ni++)
            bfr[ni] = *(const bf16x8*)&sm.Bs[(size_t)(brow[ni] + (cbase ^ brx[ni]))*8];
        #pragma unroll
        for (int mi=0;mi<4;mi++)
            #pragma unroll
            for (int ni=0;ni<2;ni++)
                acc[mi][ni] = __builtin_amdgcn_mfma_f32_16x16x32_bf16(af[mi], bfr[ni], acc[mi][ni], 0, 0, 0);
        #pragma unroll
        for (int mi=0;mi<4;mi++) af[mi] = an[mi];
    }
    __syncthreads();   // done with Bs; overlay Y
    #pragma unroll
    for (int mi=0;mi<4;mi++)
        #pragma unroll
        for (int ni=0;ni<2;ni++)
            #pragma unroll
            for (int r=0;r<4;r++){
                int o = wv*64 + mi*16 + (lane>>4)*4 + r;
                int n = ni*16 + (lane&15);
                sm.Y[o*33 + n] = acc[mi][ni][r];
            }
    __syncthreads();
    int n = t & 31, q = t >> 5;              // 8 o-groups of 32
    float s = 0.f, s2 = 0.f;
    for (int o=32*q; o<32*q+32; o++){
        float y = sm.Y[o*33+n] + bout[o];
        s += y; s2 += y*y;
    }
    red[0][q][n] = s; red[1][q][n] = s2;
    __syncthreads();
    if (t < 32){
        float S = 0.f, S2 = 0.f;
        #pragma unroll
        for (int p=0;p<8;p++){ S += red[0][p][t]; S2 += red[1][p][t]; }
        float mu = S * (1.f/256.f);
        float var = S2*(1.f/256.f) - mu*mu;
        mu_s[t] = mu; rstd_s[t] = rsqrtf(var + 1e-5f);
    }
    __syncthreads();
    float mu = mu_s[n], rstd = rstd_s[n];
    size_t ob = (size_t)b*CDIM*NSP + n0 + n;
    for (int o=32*q; o<32*q+32; o++){
        float y = sm.Y[o*33+n] + bout[o];
        out[ob + (size_t)o*NSP] = (y - mu)*rstd*gamma[o] + beta[o];
    }
}

extern "C" void kernel_launch(void* const* d_in, const int* in_sizes, int n_in,
                              void* d_out, int out_size, void* d_ws, size_t ws_size,
                              hipStream_t stream){
    const float* x     = (const float*)d_in[0];
    const float* w_qkv = (const float*)d_in[1];
    const float* w_out = (const float*)d_in[2];
    const float* b_out = (const float*)d_in[3];
    const float* gamma = (const float*)d_in[4];
    const float* beta  = (const float*)d_in[5];
    float* out = (float*)d_out;
    char* ws = (char*)d_ws;
    // ws layout (bytes):
    //   xT    bf16 [16][4096][256] : 0          .. 33,554,432   (dead after k_qkv)
    //   ctx_p f32  [128][32][1024] : 0          .. 16,777,216   (overlaps dead xT)
    //   qT    bf16 [16][4096][256] : 33,554,432 .. 67,108,864
    //   kv    bf16 [16][512][4096] : 67,108,864 .. 134,217,728
    //   W2    bf16 [16][256][256]  : 134,742,016 .. 136,839,168
    //   w2    bf16 [768][256]      : 136,839,168 .. 137,232,384
    bf16*  xT    = (bf16*) ws;
    float* ctx_p = (float*)ws;
    bf16*  qT    = (bf16*)(ws + 33554432ull);
    bf16*  kv    = (bf16*)(ws + 67108864ull);
    bf16*  W2    = (bf16*)(ws + 134742016ull);
    bf16*  w2    = (bf16*)(ws + 136839168ull);

    k_wcvt     <<<dim3(192),       256, 0, stream>>>(w_qkv, w2);
    k_transpose<<<dim3(64, 4, NB), 256, 0, stream>>>(x, xT);
    k_qkv      <<<dim3(1536),      256, 0, stream>>>(w2, xT, qT, kv);
    k_context  <<<dim3(1024),      256, 0, stream>>>(kv, ctx_p);
    k_merge    <<<dim3(128),       256, 0, stream>>>(w_out, ctx_p, W2);
    k_out_ln   <<<dim3(2048),      256, 0, stream>>>(W2, qT, b_out, gamma, beta, out);
}

// Round 6
// 267.020 us; speedup vs baseline: 1.0569x; 1.0005x over previous
//
#include <hip/hip_runtime.h>
#include <hip/hip_bf16.h>

#define NB 16
#define CDIM 256
#define NHEADS 8
#define DH 32
#define NSP 4096
#define O3 768

typedef __bf16 bf16;
typedef bf16 bf16x4 __attribute__((ext_vector_type(4)));
typedef bf16 bf16x8 __attribute__((ext_vector_type(8)));
typedef float f32x4 __attribute__((ext_vector_type(4)));
typedef float f32x16 __attribute__((ext_vector_type(16)));

static __device__ __forceinline__ float bf2f(bf16 x){ return (float)x; }
static __device__ __forceinline__ bf16 f2bf(float x){ return (bf16)x; }

// async global->LDS, 16B per lane; lds dst wave-uniform base + lane*16
static __device__ __forceinline__ void gld16(const bf16* g, bf16* l){
    __builtin_amdgcn_global_load_lds((const __attribute__((address_space(1))) void*)g,
                                     (__attribute__((address_space(3))) void*)l, 16, 0, 0);
}

// ---------------- K0: transpose+convert x[b][c][n] (fp32) -> xT[b][n][c] (bf16) ----------------
__global__ void k_transpose(const float* __restrict__ x, bf16* __restrict__ xT){
    __shared__ bf16 tile[64][72];
    int b = blockIdx.z;
    int c0 = blockIdx.y * 64;
    int n0 = blockIdx.x * 64;
    int t = threadIdx.x;
    const float* xb = x + (size_t)b * CDIM * NSP;
    #pragma unroll
    for (int i = 0; i < 4; ++i){
        int lin = i*256 + t;
        int c = lin >> 4;
        int n4 = (lin & 15) * 4;
        f32x4 f = *(const f32x4*)(xb + (size_t)(c0 + c)*NSP + n0 + n4);
        bf16x4 v4;
        #pragma unroll
        for (int j = 0; j < 4; ++j) v4[j] = f2bf(f[j]);
        *(bf16x4*)&tile[c][n4] = v4;
    }
    __syncthreads();
    bf16* xTb = xT + (size_t)b * NSP * CDIM;
    #pragma unroll
    for (int i = 0; i < 2; ++i){
        int lin = i*256 + t;
        int n = lin >> 3;
        int c8 = (lin & 7) * 8;
        bf16x8 v;
        #pragma unroll
        for (int j = 0; j < 8; ++j) v[j] = tile[c8+j][n];
        *(bf16x8*)(xTb + (size_t)(n0+n)*CDIM + c0 + c8) = v;
    }
}

// ---------------- K0b: convert w_qkv fp32 -> bf16 ----------------
__global__ void k_wcvt(const float* __restrict__ w, bf16* __restrict__ w2){
    int idx = (blockIdx.x*256 + threadIdx.x) * 4;
    f32x4 f = *(const f32x4*)(w + idx);
    bf16x4 v;
    #pragma unroll
    for (int j=0;j<4;j++) v[j] = f2bf(f[j]);
    *(bf16x4*)(w2 + idx) = v;
}

// ---------------- K1: q GEMM + q softmax -> qT. R1-verified code restricted to m in {0,1}. ----
// Block: 128-n panel (64KB staged once) x 128 q-rows. 4 waves; wave = 32 o x 128 n, acc[2][8].
__global__ __launch_bounds__(256) void k_q(const bf16* __restrict__ w2,
                                           const bf16* __restrict__ xT,
                                           bf16* __restrict__ qT){
    __shared__ union {
        bf16 Bs[32768];       // 128*32 slots * 8 el = 64 KB
        bf16 ep[128*136];     // epilogue buffer (row stride 136 el = 272B, 16B-mult)
    } sm;
    int bid = blockIdx.x;
    int xcd = bid & 7, slot = bid >> 3;      // 128 slots per XCD
    int m  = slot & 1;
    int ntile = xcd*64 + (slot >> 1);        // 0..511
    int b  = ntile >> 5;
    int n0 = (ntile & 31) * 128;
    int m0 = m * 128;
    int t = threadIdx.x;
    int wv = t >> 6, lane = t & 63;

    // ---- stage whole B panel: per wave 16 gld16 (rows wv*32 .. wv*32+31) ----
    #pragma unroll
    for (int j=0;j<16;j++){
        int base_r = wv*32 + j*2;
        int r = base_r + (lane>>5);
        int c = (lane & 31) ^ (r & 7);
        const bf16* g = xT + ((size_t)b*NSP + n0 + r)*CDIM + c*8;
        gld16(g, &sm.Bs[(size_t)base_r*256]);   // base + lane*16B covers slots base_r*32+lane
    }
    __syncthreads();

    // B-frag slot bases (k-invariant parts)
    int brow[8], brx[8];
    #pragma unroll
    for (int ni=0;ni<8;ni++){
        int r = ni*16 + (lane&15);
        brow[ni] = r*32; brx[ni] = r & 7;
    }
    int arow = m0 + wv*32 + (lane&15);      // + mi*16
    int acol = (lane>>4)*8;                  // + k0*32

    f32x4 acc[2][8];
    #pragma unroll
    for (int i=0;i<16;i++) ((f32x4*)acc)[i] = (f32x4){0.f,0.f,0.f,0.f};

    bf16x8 af0 = *(const bf16x8*)(w2 + (size_t)(arow     )*CDIM + acol);
    bf16x8 af1 = *(const bf16x8*)(w2 + (size_t)(arow + 16)*CDIM + acol);
    #pragma unroll
    for (int k0=0;k0<8;k0++){
        bf16x8 an0, an1;
        if (k0 < 7){
            an0 = *(const bf16x8*)(w2 + (size_t)(arow     )*CDIM + (k0+1)*32 + acol);
            an1 = *(const bf16x8*)(w2 + (size_t)(arow + 16)*CDIM + (k0+1)*32 + acol);
        }
        int cbase = (lane>>4) + k0*4;
        bf16x8 bfr[8];
        #pragma unroll
        for (int ni=0;ni<8;ni++)
            bfr[ni] = *(const bf16x8*)&sm.Bs[(size_t)(brow[ni] + (cbase ^ brx[ni]))*8];
        #pragma unroll
        for (int ni=0;ni<8;ni++)
            acc[0][ni] = __builtin_amdgcn_mfma_f32_16x16x32_bf16(af0, bfr[ni], acc[0][ni], 0, 0, 0);
        #pragma unroll
        for (int ni=0;ni<8;ni++)
            acc[1][ni] = __builtin_amdgcn_mfma_f32_16x16x32_bf16(af1, bfr[ni], acc[1][ni], 0, 0, 0);
        af0 = an0; af1 = an1;
    }
    __syncthreads();   // all waves done with Bs; safe to overlay ep

    // ---- fused q softmax over d (wave's 32 rows == one head): lanes xor 16,32 ----
    #pragma unroll
    for (int ni=0;ni<8;ni++){
        float mx = -1e30f;
        #pragma unroll
        for (int mi=0;mi<2;mi++)
            #pragma unroll
            for (int r=0;r<4;r++) mx = fmaxf(mx, acc[mi][ni][r]);
        mx = fmaxf(mx, __shfl_xor(mx, 16, 64));
        mx = fmaxf(mx, __shfl_xor(mx, 32, 64));
        float s = 0.f;
        #pragma unroll
        for (int mi=0;mi<2;mi++)
            #pragma unroll
            for (int r=0;r<4;r++){
                float e = __expf(acc[mi][ni][r] - mx);
                acc[mi][ni][r] = e; s += e;
            }
        s += __shfl_xor(s, 16, 64);
        s += __shfl_xor(s, 32, 64);
        float inv = 1.f/s;
        #pragma unroll
        for (int mi=0;mi<2;mi++)
            #pragma unroll
            for (int r=0;r<4;r++) acc[mi][ni][r] *= inv;
    }
    // dump transposed: ep[n_loc][o_loc], b64 stores
    #pragma unroll
    for (int mi=0;mi<2;mi++)
        #pragma unroll
        for (int ni=0;ni<8;ni++){
            int n_loc = ni*16 + (lane&15);
            int o_loc = wv*32 + mi*16 + (lane>>4)*4;
            bf16x4 v4;
            #pragma unroll
            for (int r=0;r<4;r++) v4[r] = f2bf(acc[mi][ni][r]);
            *(bf16x4*)&sm.ep[n_loc*136 + o_loc] = v4;
        }
    __syncthreads();
    bf16* qTb = qT + (size_t)b * NSP * CDIM;
    #pragma unroll
    for (int p=0;p<8;p++){
        int task = p*256 + t;
        int n_loc = task >> 4, seg = task & 15;
        bf16x8 v = *(const bf16x8*)&sm.ep[n_loc*136 + seg*8];
        *(bf16x8*)(qTb + (size_t)(n0+n_loc)*CDIM + m0 + seg*8) = v;
    }
}

// ---------------- K2: fused k/v GEMM + k softmax + context partials ----------------
// Block: one 64-n panel (one y-line, 32KB LDS) x all 512 k/v rows. 1024 thr = 16 waves;
// wave = 32 o x 64 n, acc[2][4]. Waves 0-7: k rows (o 256..511), waves 8-15: v (512..767).
// After GEMM: k softmax (block-local y-line), then 2 phases x 4 heads:
//   dump k_sm/v to LDS (XOR-swizzled [128][64] each), ctx partial via mfma 32x32x16,
//   write fp32 partials ctx_p[b][h][ntloc][32][32].  kv never touches HBM.
__global__ __launch_bounds__(1024,4) void k_kvctx(const bf16* __restrict__ w2,
                                                  const bf16* __restrict__ xT,
                                                  float* __restrict__ ctx_p){
    __shared__ union {
        bf16 Bs[16384];      // 64 rows * 32 slots * 8 el = 32 KB
        bf16 cb[16384];      // k_sm[128][64] @ el 0, v[128][64] @ el 8192
    } sm;
    int bid = blockIdx.x;
    int xcd = bid & 7, slot = bid >> 3;      // 128 slots per XCD
    int g = xcd*128 + slot;                  // 0..1023
    int b = g >> 6;
    int ntloc = g & 63;
    int n0 = ntloc * 64;
    int t = threadIdx.x;
    int wv = t >> 6, lane = t & 63;

    // ---- stage panel [64 n][256 c]: per wave 2 gld16 (rows wv*4 .. wv*4+3) ----
    #pragma unroll
    for (int j=0;j<2;j++){
        int base_r = wv*4 + j*2;
        int r = base_r + (lane>>5);
        int c = (lane & 31) ^ (r & 7);
        gld16(xT + ((size_t)b*NSP + n0 + r)*CDIM + c*8, &sm.Bs[(size_t)base_r*256]);
    }
    __syncthreads();

    int brow[4], brx[4];
    #pragma unroll
    for (int ni=0;ni<4;ni++){
        int r = ni*16 + (lane&15);
        brow[ni] = r*32; brx[ni] = r & 7;
    }
    int arow = 256 + wv*32 + (lane&15);      // waves 0-7: k (256..511); 8-15: v (512..767)
    int acol = (lane>>4)*8;

    f32x4 acc[2][4];
    #pragma unroll
    for (int i=0;i<8;i++) ((f32x4*)acc)[i] = (f32x4){0.f,0.f,0.f,0.f};

    bf16x8 af0 = *(const bf16x8*)(w2 + (size_t)(arow     )*CDIM + acol);
    bf16x8 af1 = *(const bf16x8*)(w2 + (size_t)(arow + 16)*CDIM + acol);
    #pragma unroll
    for (int k0=0;k0<8;k0++){
        bf16x8 an0, an1;
        if (k0 < 7){
            an0 = *(const bf16x8*)(w2 + (size_t)(arow     )*CDIM + (k0+1)*32 + acol);
            an1 = *(const bf16x8*)(w2 + (size_t)(arow + 16)*CDIM + (k0+1)*32 + acol);
        }
        int cbase = (lane>>4) + k0*4;
        bf16x8 bfr[4];
        #pragma unroll
        for (int ni=0;ni<4;ni++)
            bfr[ni] = *(const bf16x8*)&sm.Bs[(size_t)(brow[ni] + (cbase ^ brx[ni]))*8];
        #pragma unroll
        for (int ni=0;ni<4;ni++)
            acc[0][ni] = __builtin_amdgcn_mfma_f32_16x16x32_bf16(af0, bfr[ni], acc[0][ni], 0, 0, 0);
        #pragma unroll
        for (int ni=0;ni<4;ni++)
            acc[1][ni] = __builtin_amdgcn_mfma_f32_16x16x32_bf16(af1, bfr[ni], acc[1][ni], 0, 0, 0);
        af0 = an0; af1 = an1;
    }

    // ---- k softmax over the 64-wide y-line (waves 0-7 only): 4 ni x 16 lanes ----
    if (wv < 8){
        #pragma unroll
        for (int mi=0;mi<2;mi++)
            #pragma unroll
            for (int r=0;r<4;r++){
                float mx = -1e30f;
                #pragma unroll
                for (int ni=0;ni<4;ni++) mx = fmaxf(mx, acc[mi][ni][r]);
                #pragma unroll
                for (int msk=1; msk<16; msk<<=1) mx = fmaxf(mx, __shfl_xor(mx, msk, 64));
                float s = 0.f;
                #pragma unroll
                for (int ni=0;ni<4;ni++){
                    float e = __expf(acc[mi][ni][r] - mx);
                    acc[mi][ni][r] = e; s += e;
                }
                #pragma unroll
                for (int msk=1; msk<16; msk<<=1) s += __shfl_xor(s, msk, 64);
                float inv = 1.f/s;
                #pragma unroll
                for (int ni=0;ni<4;ni++) acc[mi][ni][r] *= inv;
            }
    }

    // ---- two phases: dump 4 heads of k_sm + v, then ctx partial MFMA ----
    #pragma unroll
    for (int ph=0; ph<2; ++ph){
        __syncthreads();   // LDS (Bs or prev-phase cb) free
        int isv  = wv >> 3;          // 0 = k group, 1 = v group
        int wloc = wv & 7;           // wave index within group
        if ((wloc >> 2) == ph){      // 4 dumping waves per group per phase
            int base = isv * 8192;
            int w03 = wloc & 3;
            #pragma unroll
            for (int mi=0;mi<2;mi++)
                #pragma unroll
                for (int ni=0;ni<4;ni++)
                    #pragma unroll
                    for (int r=0;r<4;r++){
                        int row = w03*32 + mi*16 + (lane>>4)*4 + r;   // 0..127 in-phase
                        int n = ni*16 + (lane&15);
                        sm.cb[base + row*64 + (((n>>3) ^ (row&7))<<3) + (n&7)] = f2bf(acc[mi][ni][r]);
                    }
        }
        __syncthreads();
        if (wv < 4){
            // ctx for head h = ph*4 + wv:  ctx[d][e] = sum_n k_sm[d][n] * v[e][n]
            f32x16 cacc;
            #pragma unroll
            for (int i=0;i<16;i++) cacc[i] = 0.f;
            int rr = wv*32 + (lane&31);
            int swz = (rr & 7) << 3;
            #pragma unroll
            for (int s=0;s<4;s++){
                int nseg = s*2 + (lane>>5);
                int off = rr*64 + (((nseg<<3) ^ swz));
                bf16x8 ka = *(const bf16x8*)&sm.cb[off];
                bf16x8 vb = *(const bf16x8*)&sm.cb[8192 + off];
                cacc = __builtin_amdgcn_mfma_f32_32x32x16_bf16(ka, vb, cacc, 0, 0, 0);
            }
            float* dst = ctx_p + ((size_t)(b*8 + ph*4 + wv)*64 + ntloc)*1024;
            #pragma unroll
            for (int r=0;r<16;r++){
                int d = (r&3) + 8*(r>>2) + 4*(lane>>5);
                dst[d*32 + (lane&31)] = cacc[r];
            }
        }
    }
}

// ---------------- K5: reduce 64 partials + W2 = w_out x ctx (per b,h) ----------------
__global__ void k_merge(const float* __restrict__ w_out, const float* __restrict__ ctx_p,
                        bf16* __restrict__ W2){
    __shared__ float ctxs[32][32];
    int bh = blockIdx.x;
    int b = bh >> 3, h = bh & 7;
    int t = threadIdx.x;
    const float* base = ctx_p + (size_t)bh*64*1024;
    #pragma unroll
    for (int i=0;i<4;i++){
        int idx = i*256 + t;
        float s = 0.f;
        for (int p=0;p<64;p++) s += base[p*1024 + idx];
        ((float*)ctxs)[idx] = s;
    }
    __syncthreads();
    int o = t;
    const float* wrow = w_out + (size_t)o*CDIM + h*DH;
    float wv[32];
    #pragma unroll
    for (int d=0;d<32;d++) wv[d] = wrow[d];
    bf16* dst = W2 + ((size_t)b*CDIM + o)*CDIM + h*DH;
    #pragma unroll
    for (int g=0;g<4;g++){
        bf16x8 o8;
        #pragma unroll
        for (int jj=0;jj<8;jj++){
            int e = g*8 + jj;
            float s = 0.f;
            #pragma unroll
            for (int d=0;d<32;d++) s += wv[d]*ctxs[d][e];
            o8[jj] = f2bf(s);
        }
        *(bf16x8*)(dst + g*8) = o8;
    }
}

// ---------------- K6: y = W2[b] @ q~T + b_out + LayerNorm; 32-n panel (36KB LDS) ----------------
__global__ __launch_bounds__(256,4) void k_out_ln(const bf16* __restrict__ W2,
                                                  const bf16* __restrict__ qT,
                                                  const float* __restrict__ bout,
                                                  const float* __restrict__ gamma,
                                                  const float* __restrict__ beta,
                                                  float* __restrict__ out){
    __shared__ union {
        bf16 Bs[8192];       // 32 rows * 32 slots * 8 el = 16 KB
        float Y[256*33];     // 33.8 KB
    } sm;
    __shared__ float red[2][8][32];
    __shared__ float mu_s[32], rstd_s[32];
    int bid = blockIdx.x;
    int xcd = bid & 7, slot = bid >> 3;      // 256 slots per XCD
    int b  = slot >> 4;
    int n0 = (xcd*16 + (slot & 15)) * 32;
    int t = threadIdx.x, wv = t>>6, lane = t&63;

    // ---- stage qT panel [n0..n0+32][0..256]: per wave 4 gld16 (rows wv*8..wv*8+7) ----
    const bf16* qTb = qT + (size_t)b * NSP * CDIM;
    #pragma unroll
    for (int j=0;j<4;j++){
        int base_r = wv*8 + j*2;
        int r = base_r + (lane>>5);
        int c = (lane & 31) ^ (r & 7);
        gld16(qTb + (size_t)(n0 + r)*CDIM + c*8, &sm.Bs[(size_t)base_r*256]);
    }
    __syncthreads();

    int brow[2], brx[2];
    #pragma unroll
    for (int ni=0;ni<2;ni++){
        int r = ni*16 + (lane&15);
        brow[ni] = r*32; brx[ni] = r & 7;
    }
    const bf16* Ab = W2 + (size_t)b*CDIM*CDIM;
    int arow = wv*64 + (lane&15);
    int acol = (lane>>4)*8;

    f32x4 acc[4][2];
    #pragma unroll
    for (int i=0;i<8;i++) ((f32x4*)acc)[i] = (f32x4){0.f,0.f,0.f,0.f};

    bf16x8 af[4], an[4];
    #pragma unroll
    for (int mi=0;mi<4;mi++)
        af[mi] = *(const bf16x8*)(Ab + (size_t)(arow + mi*16)*CDIM + acol);
    #pragma unroll
    for (int k0=0;k0<8;k0++){
        if (k0 < 7){
            #pragma unroll
            for (int mi=0;mi<4;mi++)
                an[mi] = *(const bf16x8*)(Ab + (size_t)(arow + mi*16)*CDIM + (k0+1)*32 + acol);
        }
        int cbase = (lane>>4) + k0*4;
        bf16x8 bfr[2];
        #pragma unroll
        for (int ni=0;ni<2;ni++)
            bfr[ni] = *(const bf16x8*)&sm.Bs[(size_t)(brow[ni] + (cbase ^ brx[ni]))*8];
        #pragma unroll
        for (int mi=0;mi<4;mi++)
            #pragma unroll
            for (int ni=0;ni<2;ni++)
                acc[mi][ni] = __builtin_amdgcn_mfma_f32_16x16x32_bf16(af[mi], bfr[ni], acc[mi][ni], 0, 0, 0);
        #pragma unroll
        for (int mi=0;mi<4;mi++) af[mi] = an[mi];
    }
    __syncthreads();   // done with Bs; overlay Y
    #pragma unroll
    for (int mi=0;mi<4;mi++)
        #pragma unroll
        for (int ni=0;ni<2;ni++)
            #pragma unroll
            for (int r=0;r<4;r++){
                int o = wv*64 + mi*16 + (lane>>4)*4 + r;
                int n = ni*16 + (lane&15);
                sm.Y[o*33 + n] = acc[mi][ni][r];
            }
    __syncthreads();
    int n = t & 31, q = t >> 5;              // 8 o-groups of 32
    float s = 0.f, s2 = 0.f;
    for (int o=32*q; o<32*q+32; o++){
        float y = sm.Y[o*33+n] + bout[o];
        s += y; s2 += y*y;
    }
    red[0][q][n] = s; red[1][q][n] = s2;
    __syncthreads();
    if (t < 32){
        float S = 0.f, S2 = 0.f;
        #pragma unroll
        for (int p=0;p<8;p++){ S += red[0][p][t]; S2 += red[1][p][t]; }
        float mu = S * (1.f/256.f);
        float var = S2*(1.f/256.f) - mu*mu;
        mu_s[t] = mu; rstd_s[t] = rsqrtf(var + 1e-5f);
    }
    __syncthreads();
    float mu = mu_s[n], rstd = rstd_s[n];
    size_t ob = (size_t)b*CDIM*NSP + n0 + n;
    for (int o=32*q; o<32*q+32; o++){
        float y = sm.Y[o*33+n] + bout[o];
        out[ob + (size_t)o*NSP] = (y - mu)*rstd*gamma[o] + beta[o];
    }
}

extern "C" void kernel_launch(void* const* d_in, const int* in_sizes, int n_in,
                              void* d_out, int out_size, void* d_ws, size_t ws_size,
                              hipStream_t stream){
    const float* x     = (const float*)d_in[0];
    const float* w_qkv = (const float*)d_in[1];
    const float* w_out = (const float*)d_in[2];
    const float* b_out = (const float*)d_in[3];
    const float* gamma = (const float*)d_in[4];
    const float* beta  = (const float*)d_in[5];
    float* out = (float*)d_out;
    char* ws = (char*)d_ws;
    // ws layout (bytes):
    //   xT    bf16 [16][4096][256]     : 0          .. 33,554,432
    //   qT    bf16 [16][4096][256]     : 33,554,432 .. 67,108,864
    //   ctx_p f32  [128][64][1024]     : 67,108,864 .. 100,663,296   (kv buffer eliminated)
    //   W2    bf16 [16][256][256]      : 134,742,016 .. 136,839,168
    //   w2    bf16 [768][256]          : 136,839,168 .. 137,232,384
    bf16*  xT    = (bf16*) ws;
    bf16*  qT    = (bf16*)(ws + 33554432ull);
    float* ctx_p = (float*)(ws + 67108864ull);
    bf16*  W2    = (bf16*)(ws + 134742016ull);
    bf16*  w2    = (bf16*)(ws + 136839168ull);

    k_wcvt     <<<dim3(192),       256,  0, stream>>>(w_qkv, w2);
    k_transpose<<<dim3(64, 4, NB), 256,  0, stream>>>(x, xT);
    k_kvctx    <<<dim3(1024),      1024, 0, stream>>>(w2, xT, ctx_p);
    k_q        <<<dim3(1024),      256,  0, stream>>>(w2, xT, qT);
    k_merge    <<<dim3(128),       256,  0, stream>>>(w_out, ctx_p, W2);
    k_out_ln   <<<dim3(2048),      256,  0, stream>>>(W2, qT, b_out, gamma, beta, out);
}

// Round 7
// 236.292 us; speedup vs baseline: 1.1943x; 1.1300x over previous
//
#include <hip/hip_runtime.h>
#include <hip/hip_bf16.h>

#define NB 16
#define CDIM 256
#define NHEADS 8
#define DH 32
#define NSP 4096
#define O3 768

typedef __bf16 bf16;
typedef bf16 bf16x4 __attribute__((ext_vector_type(4)));
typedef bf16 bf16x8 __attribute__((ext_vector_type(8)));
typedef float f32x4 __attribute__((ext_vector_type(4)));
typedef float f32x16 __attribute__((ext_vector_type(16)));

static __device__ __forceinline__ float bf2f(bf16 x){ return (float)x; }
static __device__ __forceinline__ bf16 f2bf(float x){ return (bf16)x; }

// async global->LDS, 16B per lane; lds dst wave-uniform base + lane*16
static __device__ __forceinline__ void gld16(const bf16* g, bf16* l){
    __builtin_amdgcn_global_load_lds((const __attribute__((address_space(1))) void*)g,
                                     (__attribute__((address_space(3))) void*)l, 16, 0, 0);
}

// ---------------- K0: transpose+convert x[b][c][n] (fp32) -> xT[b][n][c] (bf16) ----------------
__global__ void k_transpose(const float* __restrict__ x, bf16* __restrict__ xT){
    __shared__ bf16 tile[64][72];
    int b = blockIdx.z;
    int c0 = blockIdx.y * 64;
    int n0 = blockIdx.x * 64;
    int t = threadIdx.x;
    const float* xb = x + (size_t)b * CDIM * NSP;
    #pragma unroll
    for (int i = 0; i < 4; ++i){
        int lin = i*256 + t;
        int c = lin >> 4;
        int n4 = (lin & 15) * 4;
        f32x4 f = *(const f32x4*)(xb + (size_t)(c0 + c)*NSP + n0 + n4);
        bf16x4 v4;
        #pragma unroll
        for (int j = 0; j < 4; ++j) v4[j] = f2bf(f[j]);
        *(bf16x4*)&tile[c][n4] = v4;
    }
    __syncthreads();
    bf16* xTb = xT + (size_t)b * NSP * CDIM;
    #pragma unroll
    for (int i = 0; i < 2; ++i){
        int lin = i*256 + t;
        int n = lin >> 3;
        int c8 = (lin & 7) * 8;
        bf16x8 v;
        #pragma unroll
        for (int j = 0; j < 8; ++j) v[j] = tile[c8+j][n];
        *(bf16x8*)(xTb + (size_t)(n0+n)*CDIM + c0 + c8) = v;
    }
}

// ---------------- K0b: convert w_qkv fp32 -> bf16 ----------------
__global__ void k_wcvt(const float* __restrict__ w, bf16* __restrict__ w2){
    int idx = (blockIdx.x*256 + threadIdx.x) * 4;
    f32x4 f = *(const f32x4*)(w + idx);
    bf16x4 v;
    #pragma unroll
    for (int j=0;j<4;j++) v[j] = f2bf(f[j]);
    *(bf16x4*)(w2 + idx) = v;
}

// ---------------- K1: q GEMM + softmax -> qT. 512 blocks x 512 thr; panel staged ONCE. ----
// Block: 128-n panel (64KB) x all 256 q-rows. 8 waves; wave = 32 o x 128 n, acc[2][8].
// Epilogue: 2 n-phases through ep[64][264] (33.8KB), full 256-wide qT row writes.
__global__ __launch_bounds__(512) void k_q(const bf16* __restrict__ w2,
                                           const bf16* __restrict__ xT,
                                           bf16* __restrict__ qT){
    __shared__ union {
        bf16 Bs[32768];       // 128*32 slots * 8 el = 64 KB
        bf16 ep[64*264];      // 33.8 KB epilogue buffer
    } sm;
    int bid = blockIdx.x;
    int xcd = bid & 7, slot = bid >> 3;      // 64 slots per XCD
    int g = xcd*64 + slot;                   // 0..511
    int b  = g >> 5;
    int n0 = (g & 31) * 128;
    int t = threadIdx.x;
    int wv = t >> 6, lane = t & 63;

    // ---- stage whole B panel: per wave 8 gld16 (rows wv*16 .. wv*16+15) ----
    #pragma unroll
    for (int j=0;j<8;j++){
        int base_r = wv*16 + j*2;
        int r = base_r + (lane>>5);
        int c = (lane & 31) ^ (r & 7);
        gld16(xT + ((size_t)b*NSP + n0 + r)*CDIM + c*8, &sm.Bs[(size_t)base_r*256]);
    }
    __syncthreads();

    int brow[8], brx[8];
    #pragma unroll
    for (int ni=0;ni<8;ni++){
        int r = ni*16 + (lane&15);
        brow[ni] = r*32; brx[ni] = r & 7;
    }
    int arow = wv*32 + (lane&15);            // q rows 0..255; + mi*16
    int acol = (lane>>4)*8;

    f32x4 acc[2][8];
    #pragma unroll
    for (int i=0;i<16;i++) ((f32x4*)acc)[i] = (f32x4){0.f,0.f,0.f,0.f};

    bf16x8 af0 = *(const bf16x8*)(w2 + (size_t)(arow     )*CDIM + acol);
    bf16x8 af1 = *(const bf16x8*)(w2 + (size_t)(arow + 16)*CDIM + acol);
    #pragma unroll
    for (int k0=0;k0<8;k0++){
        bf16x8 an0, an1;
        if (k0 < 7){
            an0 = *(const bf16x8*)(w2 + (size_t)(arow     )*CDIM + (k0+1)*32 + acol);
            an1 = *(const bf16x8*)(w2 + (size_t)(arow + 16)*CDIM + (k0+1)*32 + acol);
        }
        int cbase = (lane>>4) + k0*4;
        bf16x8 bfr[8];
        #pragma unroll
        for (int ni=0;ni<8;ni++)
            bfr[ni] = *(const bf16x8*)&sm.Bs[(size_t)(brow[ni] + (cbase ^ brx[ni]))*8];
        #pragma unroll
        for (int ni=0;ni<8;ni++)
            acc[0][ni] = __builtin_amdgcn_mfma_f32_16x16x32_bf16(af0, bfr[ni], acc[0][ni], 0, 0, 0);
        #pragma unroll
        for (int ni=0;ni<8;ni++)
            acc[1][ni] = __builtin_amdgcn_mfma_f32_16x16x32_bf16(af1, bfr[ni], acc[1][ni], 0, 0, 0);
        af0 = an0; af1 = an1;
    }

    // ---- fused q softmax over d (wave's 32 rows == one head): lanes xor 16,32 ----
    #pragma unroll
    for (int ni=0;ni<8;ni++){
        float mx = -1e30f;
        #pragma unroll
        for (int mi=0;mi<2;mi++)
            #pragma unroll
            for (int r=0;r<4;r++) mx = fmaxf(mx, acc[mi][ni][r]);
        mx = fmaxf(mx, __shfl_xor(mx, 16, 64));
        mx = fmaxf(mx, __shfl_xor(mx, 32, 64));
        float s = 0.f;
        #pragma unroll
        for (int mi=0;mi<2;mi++)
            #pragma unroll
            for (int r=0;r<4;r++){
                float e = __expf(acc[mi][ni][r] - mx);
                acc[mi][ni][r] = e; s += e;
            }
        s += __shfl_xor(s, 16, 64);
        s += __shfl_xor(s, 32, 64);
        float inv = 1.f/s;
        #pragma unroll
        for (int mi=0;mi<2;mi++)
            #pragma unroll
            for (int r=0;r<4;r++) acc[mi][ni][r] *= inv;
    }

    bf16* qTb = qT + (size_t)b * NSP * CDIM;
    // two n-phases: ph covers n-rows ph*64..ph*64+63 (ni 4ph..4ph+3)
    #pragma unroll
    for (int ph=0; ph<2; ++ph){
        __syncthreads();   // Bs dead (ph0) / prev ep read done (ph1)
        #pragma unroll
        for (int mi=0;mi<2;mi++)
            #pragma unroll
            for (int q=0;q<4;q++){
                int ni = ph*4 + q;
                int n_loc = q*16 + (lane&15);
                int o_loc = wv*32 + mi*16 + (lane>>4)*4;
                bf16x4 v4;
                #pragma unroll
                for (int r=0;r<4;r++) v4[r] = f2bf(acc[mi][ni][r]);
                *(bf16x4*)&sm.ep[n_loc*264 + o_loc] = v4;
            }
        __syncthreads();
        // 64 rows x 32 segs = 2048 tasks / 512 thr = 4 each; full 256-wide rows
        #pragma unroll
        for (int i=0;i<4;i++){
            int task = i*512 + t;
            int n_loc = task >> 5, seg = task & 31;
            bf16x8 v = *(const bf16x8*)&sm.ep[n_loc*264 + seg*8];
            *(bf16x8*)(qTb + (size_t)(n0 + ph*64 + n_loc)*CDIM + seg*8) = v;
        }
    }
}

// ---------------- K2: fused k/v GEMM + k softmax + context partials, 128-n panels ----------------
// Block: one 128-n panel (64KB Bs) x all 512 k/v rows. 1024 thr = 16 waves;
// wave = 32 o x 128 n, acc[2][8], 128 MFMA. Waves 0-7: k (rows 256..511), 8-15: v (512..767).
// k softmax per 64-wide y-line (two lines per panel, R1 grp pattern).
// 2 phases x 4 heads: dump k_sm/v to cb[128][128] each (XOR-swz, 64KB), ctx via mfma 32x32x16
// (8 MFMA per head over n=128), write fp32 partials ctx_p[b][h][ntile][32][32]. kv never in HBM.
__global__ __launch_bounds__(1024,4) void k_kvctx(const bf16* __restrict__ w2,
                                                  const bf16* __restrict__ xT,
                                                  float* __restrict__ ctx_p){
    __shared__ union {
        bf16 Bs[32768];      // 128 rows * 32 slots * 8 el = 64 KB
        bf16 cb[32768];      // k_sm[128][128] @ el 0, v[128][128] @ el 16384
    } sm;
    int bid = blockIdx.x;
    int xcd = bid & 7, slot = bid >> 3;      // 64 slots per XCD
    int g = xcd*64 + slot;                   // 0..511
    int b = g >> 5;
    int ntile = g & 31;
    int n0 = ntile * 128;
    int t = threadIdx.x;
    int wv = t >> 6, lane = t & 63;

    // ---- stage panel [128 n][256 c]: per wave 4 gld16 (rows wv*8 .. wv*8+7) ----
    #pragma unroll
    for (int j=0;j<4;j++){
        int base_r = wv*8 + j*2;
        int r = base_r + (lane>>5);
        int c = (lane & 31) ^ (r & 7);
        gld16(xT + ((size_t)b*NSP + n0 + r)*CDIM + c*8, &sm.Bs[(size_t)base_r*256]);
    }
    __syncthreads();

    int brow[8], brx[8];
    #pragma unroll
    for (int ni=0;ni<8;ni++){
        int r = ni*16 + (lane&15);
        brow[ni] = r*32; brx[ni] = r & 7;
    }
    int arow = 256 + wv*32 + (lane&15);      // waves 0-7: k (256..511); 8-15: v (512..767)
    int acol = (lane>>4)*8;

    f32x4 acc[2][8];
    #pragma unroll
    for (int i=0;i<16;i++) ((f32x4*)acc)[i] = (f32x4){0.f,0.f,0.f,0.f};

    bf16x8 af0 = *(const bf16x8*)(w2 + (size_t)(arow     )*CDIM + acol);
    bf16x8 af1 = *(const bf16x8*)(w2 + (size_t)(arow + 16)*CDIM + acol);
    #pragma unroll
    for (int k0=0;k0<8;k0++){
        bf16x8 an0, an1;
        if (k0 < 7){
            an0 = *(const bf16x8*)(w2 + (size_t)(arow     )*CDIM + (k0+1)*32 + acol);
            an1 = *(const bf16x8*)(w2 + (size_t)(arow + 16)*CDIM + (k0+1)*32 + acol);
        }
        int cbase = (lane>>4) + k0*4;
        bf16x8 bfr[8];
        #pragma unroll
        for (int ni=0;ni<8;ni++)
            bfr[ni] = *(const bf16x8*)&sm.Bs[(size_t)(brow[ni] + (cbase ^ brx[ni]))*8];
        #pragma unroll
        for (int ni=0;ni<8;ni++)
            acc[0][ni] = __builtin_amdgcn_mfma_f32_16x16x32_bf16(af0, bfr[ni], acc[0][ni], 0, 0, 0);
        #pragma unroll
        for (int ni=0;ni<8;ni++)
            acc[1][ni] = __builtin_amdgcn_mfma_f32_16x16x32_bf16(af1, bfr[ni], acc[1][ni], 0, 0, 0);
        af0 = an0; af1 = an1;
    }

    // ---- k softmax over y-lines (waves 0-7): grp 0 = ni 0..3 (n 0..63), grp 1 = ni 4..7 ----
    if (wv < 8){
        #pragma unroll
        for (int mi=0;mi<2;mi++)
            #pragma unroll
            for (int r=0;r<4;r++)
                #pragma unroll
                for (int grp=0;grp<2;grp++){
                    float mx = -1e30f;
                    #pragma unroll
                    for (int q=0;q<4;q++) mx = fmaxf(mx, acc[mi][grp*4+q][r]);
                    #pragma unroll
                    for (int msk=1; msk<16; msk<<=1) mx = fmaxf(mx, __shfl_xor(mx, msk, 64));
                    float s = 0.f;
                    #pragma unroll
                    for (int q=0;q<4;q++){
                        float e = __expf(acc[mi][grp*4+q][r] - mx);
                        acc[mi][grp*4+q][r] = e; s += e;
                    }
                    #pragma unroll
                    for (int msk=1; msk<16; msk<<=1) s += __shfl_xor(s, msk, 64);
                    float inv = 1.f/s;
                    #pragma unroll
                    for (int q=0;q<4;q++) acc[mi][grp*4+q][r] *= inv;
                }
    }

    // ---- 2 phases x 4 heads: dump + ctx ----
    #pragma unroll
    for (int ph=0; ph<2; ++ph){
        __syncthreads();   // Bs dead (ph0) / prev-phase cb reads done (ph1)
        if (((wv>>2)&1) == ph){       // dumping waves this phase: k wv ph*4..+3, v wv 8+ph*4..+3
            int isv  = wv >> 3;
            int w03  = wv & 3;
            int base = isv * 16384;
            #pragma unroll
            for (int mi=0;mi<2;mi++)
                #pragma unroll
                for (int ni=0;ni<8;ni++)
                    #pragma unroll
                    for (int r=0;r<4;r++){
                        int row = w03*32 + mi*16 + (lane>>4)*4 + r;   // 0..127 in-phase
                        int n = ni*16 + (lane&15);
                        sm.cb[base + row*128 + (((n>>3) ^ (row&15))<<3) + (n&7)] = f2bf(acc[mi][ni][r]);
                    }
        }
        __syncthreads();
        if (wv < 4){
            // ctx for head h = ph*4 + wv: ctx[d][e] = sum_n k_sm[d][n] * v[e][n]
            f32x16 cacc;
            #pragma unroll
            for (int i=0;i<16;i++) cacc[i] = 0.f;
            int rr = wv*32 + (lane&31);
            #pragma unroll
            for (int s=0;s<8;s++){
                int nseg = s*2 + (lane>>5);
                int off = rr*128 + (((nseg ^ (rr&15))<<3));
                bf16x8 ka = *(const bf16x8*)&sm.cb[off];
                bf16x8 vb = *(const bf16x8*)&sm.cb[16384 + off];
                cacc = __builtin_amdgcn_mfma_f32_32x32x16_bf16(ka, vb, cacc, 0, 0, 0);
            }
            float* dst = ctx_p + ((size_t)(b*8 + ph*4 + wv)*32 + ntile)*1024;
            #pragma unroll
            for (int r=0;r<16;r++){
                int d = (r&3) + 8*(r>>2) + 4*(lane>>5);
                dst[d*32 + (lane&31)] = cacc[r];
            }
        }
    }
}

// ---------------- K5: reduce 32 partials + W2 = w_out x ctx (per b,h) ----------------
__global__ void k_merge(const float* __restrict__ w_out, const float* __restrict__ ctx_p,
                        bf16* __restrict__ W2){
    __shared__ float ctxs[32][32];
    int bh = blockIdx.x;
    int b = bh >> 3, h = bh & 7;
    int t = threadIdx.x;
    const float* base = ctx_p + (size_t)bh*32*1024;
    #pragma unroll
    for (int i=0;i<4;i++){
        int idx = i*256 + t;
        float s0 = 0.f, s1 = 0.f;
        #pragma unroll
        for (int p=0;p<16;p++){ s0 += base[(2*p)*1024 + idx]; s1 += base[(2*p+1)*1024 + idx]; }
        ((float*)ctxs)[idx] = s0 + s1;
    }
    __syncthreads();
    int o = t;
    const float* wrow = w_out + (size_t)o*CDIM + h*DH;
    float wv[32];
    #pragma unroll
    for (int d=0;d<32;d++) wv[d] = wrow[d];
    bf16* dst = W2 + ((size_t)b*CDIM + o)*CDIM + h*DH;
    #pragma unroll
    for (int g=0;g<4;g++){
        bf16x8 o8;
        #pragma unroll
        for (int jj=0;jj<8;jj++){
            int e = g*8 + jj;
            float s = 0.f;
            #pragma unroll
            for (int d=0;d<32;d++) s += wv[d]*ctxs[d][e];
            o8[jj] = f2bf(s);
        }
        *(bf16x8*)(dst + g*8) = o8;
    }
}

// ---------------- K6: y = W2[b] @ q~T + b_out + LayerNorm; 32-n panel (36KB LDS) ----------------
__global__ __launch_bounds__(256,4) void k_out_ln(const bf16* __restrict__ W2,
                                                  const bf16* __restrict__ qT,
                                                  const float* __restrict__ bout,
                                                  const float* __restrict__ gamma,
                                                  const float* __restrict__ beta,
                                                  float* __restrict__ out){
    __shared__ union {
        bf16 Bs[8192];       // 32 rows * 32 slots * 8 el = 16 KB
        float Y[256*33];     // 33.8 KB
    } sm;
    __shared__ float red[2][8][32];
    __shared__ float mu_s[32], rstd_s[32];
    int bid = blockIdx.x;
    int xcd = bid & 7, slot = bid >> 3;      // 256 slots per XCD
    int b  = slot >> 4;
    int n0 = (xcd*16 + (slot & 15)) * 32;
    int t = threadIdx.x, wv = t>>6, lane = t&63;

    // ---- stage qT panel [n0..n0+32][0..256]: per wave 4 gld16 (rows wv*8..wv*8+7) ----
    const bf16* qTb = qT + (size_t)b * NSP * CDIM;
    #pragma unroll
    for (int j=0;j<4;j++){
        int base_r = wv*8 + j*2;
        int r = base_r + (lane>>5);
        int c = (lane & 31) ^ (r & 7);
        gld16(qTb + (size_t)(n0 + r)*CDIM + c*8, &sm.Bs[(size_t)base_r*256]);
    }
    __syncthreads();

    int brow[2], brx[2];
    #pragma unroll
    for (int ni=0;ni<2;ni++){
        int r = ni*16 + (lane&15);
        brow[ni] = r*32; brx[ni] = r & 7;
    }
    const bf16* Ab = W2 + (size_t)b*CDIM*CDIM;
    int arow = wv*64 + (lane&15);
    int acol = (lane>>4)*8;

    f32x4 acc[4][2];
    #pragma unroll
    for (int i=0;i<8;i++) ((f32x4*)acc)[i] = (f32x4){0.f,0.f,0.f,0.f};

    bf16x8 af[4], an[4];
    #pragma unroll
    for (int mi=0;mi<4;mi++)
        af[mi] = *(const bf16x8*)(Ab + (size_t)(arow + mi*16)*CDIM + acol);
    #pragma unroll
    for (int k0=0;k0<8;k0++){
        if (k0 < 7){
            #pragma unroll
            for (int mi=0;mi<4;mi++)
                an[mi] = *(const bf16x8*)(Ab + (size_t)(arow + mi*16)*CDIM + (k0+1)*32 + acol);
        }
        int cbase = (lane>>4) + k0*4;
        bf16x8 bfr[2];
        #pragma unroll
        for (int ni=0;ni<2;ni++)
            bfr[ni] = *(const bf16x8*)&sm.Bs[(size_t)(brow[ni] + (cbase ^ brx[ni]))*8];
        #pragma unroll
        for (int mi=0;mi<4;mi++)
            #pragma unroll
            for (int ni=0;ni<2;ni++)
                acc[mi][ni] = __builtin_amdgcn_mfma_f32_16x16x32_bf16(af[mi], bfr[ni], acc[mi][ni], 0, 0, 0);
        #pragma unroll
        for (int mi=0;mi<4;mi++) af[mi] = an[mi];
    }
    __syncthreads();   // done with Bs; overlay Y
    #pragma unroll
    for (int mi=0;mi<4;mi++)
        #pragma unroll
        for (int ni=0;ni<2;ni++)
            #pragma unroll
            for (int r=0;r<4;r++){
                int o = wv*64 + mi*16 + (lane>>4)*4 + r;
                int n = ni*16 + (lane&15);
                sm.Y[o*33 + n] = acc[mi][ni][r];
            }
    __syncthreads();
    int n = t & 31, q = t >> 5;              // 8 o-groups of 32
    float s = 0.f, s2 = 0.f;
    for (int o=32*q; o<32*q+32; o++){
        float y = sm.Y[o*33+n] + bout[o];
        s += y; s2 += y*y;
    }
    red[0][q][n] = s; red[1][q][n] = s2;
    __syncthreads();
    if (t < 32){
        float S = 0.f, S2 = 0.f;
        #pragma unroll
        for (int p=0;p<8;p++){ S += red[0][p][t]; S2 += red[1][p][t]; }
        float mu = S * (1.f/256.f);
        float var = S2*(1.f/256.f) - mu*mu;
        mu_s[t] = mu; rstd_s[t] = rsqrtf(var + 1e-5f);
    }
    __syncthreads();
    float mu = mu_s[n], rstd = rstd_s[n];
    size_t ob = (size_t)b*CDIM*NSP + n0 + n;
    for (int o=32*q; o<32*q+32; o++){
        float y = sm.Y[o*33+n] + bout[o];
        out[ob + (size_t)o*NSP] = (y - mu)*rstd*gamma[o] + beta[o];
    }
}

extern "C" void kernel_launch(void* const* d_in, const int* in_sizes, int n_in,
                              void* d_out, int out_size, void* d_ws, size_t ws_size,
                              hipStream_t stream){
    const float* x     = (const float*)d_in[0];
    const float* w_qkv = (const float*)d_in[1];
    const float* w_out = (const float*)d_in[2];
    const float* b_out = (const float*)d_in[3];
    const float* gamma = (const float*)d_in[4];
    const float* beta  = (const float*)d_in[5];
    float* out = (float*)d_out;
    char* ws = (char*)d_ws;
    // ws layout (bytes):
    //   xT    bf16 [16][4096][256]     : 0          .. 33,554,432
    //   qT    bf16 [16][4096][256]     : 33,554,432 .. 67,108,864
    //   ctx_p f32  [128][32][1024]     : 67,108,864 .. 83,886,080
    //   W2    bf16 [16][256][256]      : 134,742,016 .. 136,839,168
    //   w2    bf16 [768][256]          : 136,839,168 .. 137,232,384
    bf16*  xT    = (bf16*) ws;
    bf16*  qT    = (bf16*)(ws + 33554432ull);
    float* ctx_p = (float*)(ws + 67108864ull);
    bf16*  W2    = (bf16*)(ws + 134742016ull);
    bf16*  w2    = (bf16*)(ws + 136839168ull);

    k_wcvt     <<<dim3(192),       256,  0, stream>>>(w_qkv, w2);
    k_transpose<<<dim3(64, 4, NB), 256,  0, stream>>>(x, xT);
    k_kvctx    <<<dim3(512),       1024, 0, stream>>>(w2, xT, ctx_p);
    k_q        <<<dim3(512),       512,  0, stream>>>(w2, xT, qT);
    k_merge    <<<dim3(128),       256,  0, stream>>>(w_out, ctx_p, W2);
    k_out_ln   <<<dim3(2048),      256,  0, stream>>>(W2, qT, b_out, gamma, beta, out);
}